// Round 4
// baseline (292.018 us; speedup 1.0000x reference)
//
#include <hip/hip_runtime.h>

// Head attention, B=4 T=4096 C=1024 H=64. f32 in/out, bf16 MFMA compute.
// scores = k @ q^T (reference quirk). Barrier-free design: no LDS staging,
// B-fragments read directly from L2; proj grid-split over K with f32 partials.

typedef __attribute__((ext_vector_type(8))) short short8;
typedef __attribute__((ext_vector_type(4))) float f32x4;
typedef unsigned short u16;

#define MFMA16(A, B, C) __builtin_amdgcn_mfma_f32_16x16x32_bf16((A), (B), (C), 0, 0, 0)

__device__ __forceinline__ u16 f2b(float f) {
    unsigned int u = __builtin_bit_cast(unsigned int, f);
    u += 0x7fffu + ((u >> 16) & 1u);
    return (u16)(u >> 16);
}
__device__ __forceinline__ float b2f(u16 v) {
    return __builtin_bit_cast(float, (unsigned int)v << 16);
}

// ---------- kernel 1: W convert+transpose -> Wt[192][1024] bf16
__global__ __launch_bounds__(256) void wt_kernel(const float* __restrict__ Wk,
                                                 const float* __restrict__ Wq,
                                                 const float* __restrict__ Wv,
                                                 u16* __restrict__ Wt) {
    __shared__ u16 t[64][65];
    const int mat = blockIdx.x >> 4;
    const int rt  = blockIdx.x & 15;
    const float* W = (mat == 0) ? Wk : (mat == 1 ? Wq : Wv);
    const int tid = threadIdx.x;
#pragma unroll
    for (int i = 0; i < 16; ++i) {
        int lin = i * 256 + tid, r = lin >> 6, c = lin & 63;
        t[c][r] = f2b(W[(size_t)(rt * 64 + r) * 64 + c]);
    }
    __syncthreads();
#pragma unroll
    for (int i = 0; i < 16; ++i) {
        int lin = i * 256 + tid, n = lin >> 6, k = lin & 63;
        Wt[(size_t)(mat * 64 + n) * 1024 + rt * 64 + k] = t[n][k];
    }
}

// ---------- kernel 2: proj pass 1 — K-split x2, barrier-free, Wt frags from L2.
// grid 512: mgroup = bx>>1 (64 rows), kchunk = bx&1 (512 of K). f32 partials.
__global__ __launch_bounds__(256) void proj1_kernel(const float* __restrict__ x,
                                                    const u16* __restrict__ Wt,
                                                    float* __restrict__ Pp) {
    const int tid = threadIdx.x;
    const int w = tid >> 6, lane = tid & 63, quad = lane >> 4, l16 = lane & 15;
    const int kchunk = blockIdx.x & 1, mgroup = blockIdx.x >> 1;
    const int m = mgroup * 64 + w * 16 + l16;
    const int koff = quad * 8;
    const int kbase = kchunk * 512;

    f32x4 acc[12];
#pragma unroll
    for (int t = 0; t < 12; ++t) acc[t] = (f32x4)(0.0f);

    const float* xrow = x + (size_t)m * 1024 + kbase + koff;
    const u16* wbase = Wt + kbase + koff;

    float4 c0 = *(const float4*)(xrow);
    float4 c1 = *(const float4*)(xrow + 4);
    for (int kc = 0; kc < 16; ++kc) {
        float4 n0, n1;
        if (kc < 15) {
            n0 = *(const float4*)(xrow + (kc + 1) * 32);
            n1 = *(const float4*)(xrow + (kc + 1) * 32 + 4);
        }
        short8 a;
        a[0] = f2b(c0.x); a[1] = f2b(c0.y); a[2] = f2b(c0.z); a[3] = f2b(c0.w);
        a[4] = f2b(c1.x); a[5] = f2b(c1.y); a[6] = f2b(c1.z); a[7] = f2b(c1.w);
#pragma unroll
        for (int t = 0; t < 12; ++t) {
            short8 b = *(const short8*)(wbase + (size_t)(t * 16 + l16) * 1024 + kc * 32);
            acc[t] = MFMA16(a, b, acc[t]);
        }
        if (kc < 15) { c0 = n0; c1 = n1; }
    }

    // store f32 partials: Pp[kchunk][row][col], col = t*16+l16
    const int row = mgroup * 64 + w * 16 + quad * 4;
    float* dst = Pp + ((size_t)kchunk * 16384 + row) * 192 + l16;
#pragma unroll
    for (int t = 0; t < 12; ++t)
#pragma unroll
        for (int reg = 0; reg < 4; ++reg)
            dst[(size_t)reg * 192 + t * 16] = acc[t][reg];
}

// ---------- kernel 3: proj combine — add partials, bf16-round, write Kb/Qb/Vt
__global__ __launch_bounds__(256) void projc_kernel(const float* __restrict__ Pp,
                                                    u16* __restrict__ Kb,
                                                    u16* __restrict__ Qb,
                                                    u16* __restrict__ Vt) {
    __shared__ u16 tile[64][72];
    const int tid = threadIdx.x;
    const int r0 = blockIdx.x * 64;
    const float* P0 = Pp + (size_t)r0 * 192;
    const float* P1 = Pp + ((size_t)16384 + r0) * 192;

    for (int mtx = 0; mtx < 2; ++mtx) {
        u16* dst = mtx ? Qb : Kb;
#pragma unroll
        for (int i = 0; i < 16; ++i) {
            int lin = i * 256 + tid, r = lin >> 6, c = lin & 63;
            float v = P0[(size_t)r * 192 + mtx * 64 + c] + P1[(size_t)r * 192 + mtx * 64 + c];
            dst[(size_t)(r0 + r) * 64 + c] = f2b(v);
        }
    }
    // V transposed via LDS
#pragma unroll
    for (int i = 0; i < 16; ++i) {
        int lin = i * 256 + tid, r = lin >> 6, c = lin & 63;
        float v = P0[(size_t)r * 192 + 128 + c] + P1[(size_t)r * 192 + 128 + c];
        tile[c][r] = f2b(v);
    }
    __syncthreads();
    const int b = r0 >> 12, t0b = r0 & 4095;
#pragma unroll
    for (int i = 0; i < 2; ++i) {
        int lin = i * 256 + tid, h = lin >> 3, c8 = (lin & 7) << 3;
        *(short8*)(Vt + ((size_t)(b * 64 + h) << 12) + t0b + c8) = *(short8*)&tile[h][c8];
    }
}

// ---------- kernel 4: split-S flash attention pass 1, zero barriers.
// grid (tile=64, chunk=8, batch=4). Q/V fragments straight from L2; Ps wave-private.
__global__ __launch_bounds__(256) void attn_kernel(const u16* __restrict__ Kb,
                                                   const u16* __restrict__ Qb,
                                                   const u16* __restrict__ Vt,
                                                   u16* __restrict__ Op,
                                                   float* __restrict__ Ml) {
    const int tile = blockIdx.x, chunk = blockIdx.y, b = blockIdx.z;
    if (chunk * 8 > tile) return;
    __shared__ u16 Ps[4][16][72];                    // per-wave slabs, no cross-wave use
    const int tid = threadIdx.x;
    const int w = tid >> 6, lane = tid & 63, quad = lane >> 4, l16 = lane & 15;
    const int t0 = tile * 64;
    const int stBeg = chunk * 8;
    const int stEnd = min(chunk * 8 + 7, tile);

    short8 aK[2];
#pragma unroll
    for (int kk = 0; kk < 2; ++kk)
        aK[kk] = *(const short8*)(Kb + (size_t)((b << 12) + t0 + w * 16 + l16) * 64 + kk * 32 + quad * 8);

    float m_s[4], l_s[4];
    f32x4 O[4];
#pragma unroll
    for (int r = 0; r < 4; ++r) { m_s[r] = -1e30f; l_s[r] = 0.0f; }
#pragma unroll
    for (int nt = 0; nt < 4; ++nt) O[nt] = (f32x4)(0.0f);

    const int trow = w * 16 + quad * 4;
    const int tglob = t0 + trow;

    for (int st = stBeg; st <= stEnd; ++st) {
        const int s0 = st * 64;

        // S = K @ Q^T : B-frags from L2, short liveness
        f32x4 sc[4];
#pragma unroll
        for (int nt = 0; nt < 4; ++nt) sc[nt] = (f32x4)(0.0f);
#pragma unroll
        for (int kk = 0; kk < 2; ++kk) {
            short8 bq0 = *(const short8*)(Qb + (size_t)((b << 12) + s0 + 0 * 16 + l16) * 64 + kk * 32 + quad * 8);
            short8 bq1 = *(const short8*)(Qb + (size_t)((b << 12) + s0 + 1 * 16 + l16) * 64 + kk * 32 + quad * 8);
            short8 bq2 = *(const short8*)(Qb + (size_t)((b << 12) + s0 + 2 * 16 + l16) * 64 + kk * 32 + quad * 8);
            short8 bq3 = *(const short8*)(Qb + (size_t)((b << 12) + s0 + 3 * 16 + l16) * 64 + kk * 32 + quad * 8);
            sc[0] = MFMA16(aK[kk], bq0, sc[0]);
            sc[1] = MFMA16(aK[kk], bq1, sc[1]);
            sc[2] = MFMA16(aK[kk], bq2, sc[2]);
            sc[3] = MFMA16(aK[kk], bq3, sc[3]);
        }

        // prefetch V fragments; latency buried under softmax VALU
        short8 bv[8];
#pragma unroll
        for (int kk = 0; kk < 2; ++kk)
#pragma unroll
            for (int nt = 0; nt < 4; ++nt)
                bv[kk * 4 + nt] = *(const short8*)(Vt + ((size_t)(b * 64 + nt * 16 + l16) << 12) + s0 + kk * 32 + quad * 8);

        // scale + causal mask + row max
        float mx[4] = {-1e30f, -1e30f, -1e30f, -1e30f};
#pragma unroll
        for (int nt = 0; nt < 4; ++nt) {
            int sg = s0 + nt * 16 + l16;
#pragma unroll
            for (int reg = 0; reg < 4; ++reg) {
                float v = sc[nt][reg] * 0.125f;
                if (st == tile && sg > tglob + reg) v = -1e30f;
                sc[nt][reg] = v;
                mx[reg] = fmaxf(mx[reg], v);
            }
        }
#pragma unroll
        for (int reg = 0; reg < 4; ++reg) {
            float v = mx[reg];
            v = fmaxf(v, __shfl_xor(v, 1));
            v = fmaxf(v, __shfl_xor(v, 2));
            v = fmaxf(v, __shfl_xor(v, 4));
            v = fmaxf(v, __shfl_xor(v, 8));
            mx[reg] = v;
        }
        float alpha[4], rs[4];
#pragma unroll
        for (int reg = 0; reg < 4; ++reg) {
            float mn = fmaxf(m_s[reg], mx[reg]);
            alpha[reg] = __expf(m_s[reg] - mn);
            m_s[reg] = mn;
            l_s[reg] *= alpha[reg];
            rs[reg] = 0.0f;
        }
#pragma unroll
        for (int nt = 0; nt < 4; ++nt)
#pragma unroll
            for (int reg = 0; reg < 4; ++reg) {
                float p = __expf(sc[nt][reg] - m_s[reg]);
                rs[reg] += p;
                Ps[w][quad * 4 + reg][nt * 16 + l16] = f2b(p);   // wave-private slab
            }
#pragma unroll
        for (int reg = 0; reg < 4; ++reg) {
            float v = rs[reg];
            v += __shfl_xor(v, 1);
            v += __shfl_xor(v, 2);
            v += __shfl_xor(v, 4);
            v += __shfl_xor(v, 8);
            l_s[reg] += v;
        }
#pragma unroll
        for (int nt = 0; nt < 4; ++nt)
#pragma unroll
            for (int reg = 0; reg < 4; ++reg)
                O[nt][reg] *= alpha[reg];

        // PV: A = P from wave-private LDS (in-order DS pipe, no barrier needed)
#pragma unroll
        for (int kk = 0; kk < 2; ++kk) {
            short8 ap = *(const short8*)&Ps[w][l16][kk * 32 + quad * 8];
            O[0] = MFMA16(ap, bv[kk * 4 + 0], O[0]);
            O[1] = MFMA16(ap, bv[kk * 4 + 1], O[1]);
            O[2] = MFMA16(ap, bv[kk * 4 + 2], O[2]);
            O[3] = MFMA16(ap, bv[kk * 4 + 3], O[3]);
        }
    }

    const int slot = ((b * 64 + tile) * 8 + chunk);
    if (l16 == 0) {
#pragma unroll
        for (int reg = 0; reg < 4; ++reg) {
            Ml[(size_t)slot * 128 + trow + reg]      = m_s[reg];
            Ml[(size_t)slot * 128 + 64 + trow + reg] = l_s[reg];
        }
    }
#pragma unroll
    for (int nt = 0; nt < 4; ++nt)
#pragma unroll
        for (int reg = 0; reg < 4; ++reg)
            Op[(size_t)slot * 4096 + (size_t)(trow + reg) * 64 + nt * 16 + l16] = f2b(O[nt][reg]);
}

// ---------- kernel 5: combine attention partials -> out f32
__global__ __launch_bounds__(256) void combine_kernel(const u16* __restrict__ Op,
                                                      const float* __restrict__ Ml,
                                                      float* __restrict__ out) {
    const int tid = threadIdx.x, col = tid & 63, r0 = tid >> 6;
    const int tile = blockIdx.x >> 2, rg = blockIdx.x & 3, b = blockIdx.y;
    const int nch = tile / 8 + 1;
    const int slotBase = (b * 64 + tile) * 8;
#pragma unroll
    for (int i = 0; i < 4; ++i) {
        const int row = rg * 16 + r0 + 4 * i;
        float m[8], l[8];
        float M = -1e30f;
        for (int c = 0; c < nch; ++c) {
            m[c] = Ml[(size_t)(slotBase + c) * 128 + row];
            l[c] = Ml[(size_t)(slotBase + c) * 128 + 64 + row];
            M = fmaxf(M, m[c]);
        }
        float L = 0.0f, acc = 0.0f;
        for (int c = 0; c < nch; ++c) {
            float wgt = __expf(m[c] - M);
            L += wgt * l[c];
            acc += wgt * b2f(Op[(size_t)(slotBase + c) * 4096 + (size_t)row * 64 + col]);
        }
        out[((size_t)(b << 12) + tile * 64 + row) * 64 + col] = acc / L;
    }
}

extern "C" void kernel_launch(void* const* d_in, const int* in_sizes, int n_in,
                              void* d_out, int out_size, void* d_ws, size_t ws_size,
                              hipStream_t stream) {
    const float* x  = (const float*)d_in[0];
    const float* Wk = (const float*)d_in[1];
    const float* Wq = (const float*)d_in[2];
    const float* Wv = (const float*)d_in[3];

    u16* ws16 = (u16*)d_ws;
    u16* Wt = ws16;                          // 196608 u16  (0.4 MB)
    u16* Kb = Wt + 196608;                   // 1048576 u16 (2 MB)
    u16* Qb = Kb + 1048576;
    u16* Vt = Qb + 1048576;
    u16* trans = Vt + 1048576;               // transient region (25.2 MB):
    float* Pp = (float*)trans;               //   Pp: 2*16384*192 f32 (proj phase)
    u16* Op = trans;                         //   Op: 8388608 u16  (attn phase, aliases Pp)
    float* Ml = (float*)(Op + 8388608);      //   Ml: 262144 f32
    // total ws use ~31.9 MB; aliasing safe: projc reads Pp before attn writes Op.

    wt_kernel<<<48, 256, 0, stream>>>(Wk, Wq, Wv, Wt);
    proj1_kernel<<<512, 256, 0, stream>>>(x, Wt, Pp);
    projc_kernel<<<256, 256, 0, stream>>>(Pp, Kb, Qb, Vt);
    attn_kernel<<<dim3(64, 8, 4), 256, 0, stream>>>(Kb, Qb, Vt, Op, Ml);
    combine_kernel<<<dim3(256, 4), 256, 0, stream>>>(Op, Ml, (float*)d_out);
}

// Round 5
// 199.401 us; speedup vs baseline: 1.4645x; 1.4645x over previous
//
#include <hip/hip_runtime.h>

// Head attention, B=4 T=4096 C=1024 H=64. f32 in/out, bf16 MFMA compute.
// scores = k @ q^T (reference quirk). Design rules learned:
//  - intra-block operand reuse goes through LDS (L2 fragment reads are port-bound)
//  - global latency hidden by register prefetch across the barrier, not removed barriers
//  - K-split / S-split for occupancy; partials in bf16 to keep ws small.

typedef __attribute__((ext_vector_type(8))) short short8;
typedef __attribute__((ext_vector_type(4))) float f32x4;
typedef unsigned short u16;

#define MFMA16(A, B, C) __builtin_amdgcn_mfma_f32_16x16x32_bf16((A), (B), (C), 0, 0, 0)

__device__ __forceinline__ u16 f2b(float f) {
    unsigned int u = __builtin_bit_cast(unsigned int, f);
    u += 0x7fffu + ((u >> 16) & 1u);
    return (u16)(u >> 16);
}
__device__ __forceinline__ float b2f(u16 v) {
    return __builtin_bit_cast(float, (unsigned int)v << 16);
}

// ---------- kernel 1: W convert+transpose -> Wt[192][1024] bf16
__global__ __launch_bounds__(256) void wt_kernel(const float* __restrict__ Wk,
                                                 const float* __restrict__ Wq,
                                                 const float* __restrict__ Wv,
                                                 u16* __restrict__ Wt) {
    __shared__ u16 t[64][65];
    const int mat = blockIdx.x >> 4;
    const int rt  = blockIdx.x & 15;
    const float* W = (mat == 0) ? Wk : (mat == 1 ? Wq : Wv);
    const int tid = threadIdx.x;
#pragma unroll
    for (int i = 0; i < 16; ++i) {
        int lin = i * 256 + tid, r = lin >> 6, c = lin & 63;
        t[c][r] = f2b(W[(size_t)(rt * 64 + r) * 64 + c]);
    }
    __syncthreads();
#pragma unroll
    for (int i = 0; i < 16; ++i) {
        int lin = i * 256 + tid, n = lin >> 6, k = lin & 63;
        Wt[(size_t)(mat * 64 + n) * 1024 + rt * 64 + k] = t[n][k];
    }
}

// ---------- kernel 2: proj pass 1 — K-split x4, LDS double-buffered Wt staging.
// grid 1024: kchunk = bx&3 (256 of K), mgroup = bx>>2 (64 rows). bf16 partials.
__global__ __launch_bounds__(256) void proj1_kernel(const float* __restrict__ x,
                                                    const u16* __restrict__ Wt,
                                                    u16* __restrict__ Pp) {
    __shared__ u16 smem[2 * 192 * 36];               // 27.6 KB
    const int tid = threadIdx.x;
    const int w = tid >> 6, lane = tid & 63, quad = lane >> 4, l16 = lane & 15;
    const int kchunk = blockIdx.x & 3, mgroup = blockIdx.x >> 2;
    const int m = mgroup * 64 + w * 16 + l16;
    const int koff = quad * 8;
    const int kbase = kchunk * 256;

    f32x4 acc[12];
#pragma unroll
    for (int t = 0; t < 12; ++t) acc[t] = (f32x4)(0.0f);

    const float* xrow = x + (size_t)m * 1024 + kbase + koff;
    const int u0 = tid, u1 = tid + 256, u2 = tid + 512;  // 768 16B-units = [192][32]

    {   // stage kc=0 into buf 0
        short8 s0 = *(const short8*)(Wt + (size_t)(u0 >> 2) * 1024 + kbase + (u0 & 3) * 8);
        short8 s1 = *(const short8*)(Wt + (size_t)(u1 >> 2) * 1024 + kbase + (u1 & 3) * 8);
        short8 s2 = *(const short8*)(Wt + (size_t)(u2 >> 2) * 1024 + kbase + (u2 & 3) * 8);
        *(short8*)(smem + (u0 >> 2) * 36 + (u0 & 3) * 8) = s0;
        *(short8*)(smem + (u1 >> 2) * 36 + (u1 & 3) * 8) = s1;
        *(short8*)(smem + (u2 >> 2) * 36 + (u2 & 3) * 8) = s2;
    }
    float4 c0 = *(const float4*)(xrow);
    float4 c1 = *(const float4*)(xrow + 4);
    __syncthreads();

    for (int kc = 0; kc < 8; ++kc) {                 // 256 of K in chunks of 32
        const int cur = kc & 1, nxt = cur ^ 1;
        short8 p0, p1, p2;
        float4 n0, n1;
        if (kc < 7) {
            p0 = *(const short8*)(Wt + (size_t)(u0 >> 2) * 1024 + kbase + (kc + 1) * 32 + (u0 & 3) * 8);
            p1 = *(const short8*)(Wt + (size_t)(u1 >> 2) * 1024 + kbase + (kc + 1) * 32 + (u1 & 3) * 8);
            p2 = *(const short8*)(Wt + (size_t)(u2 >> 2) * 1024 + kbase + (kc + 1) * 32 + (u2 & 3) * 8);
            n0 = *(const float4*)(xrow + (kc + 1) * 32);
            n1 = *(const float4*)(xrow + (kc + 1) * 32 + 4);
        }
        short8 a;
        a[0] = f2b(c0.x); a[1] = f2b(c0.y); a[2] = f2b(c0.z); a[3] = f2b(c0.w);
        a[4] = f2b(c1.x); a[5] = f2b(c1.y); a[6] = f2b(c1.z); a[7] = f2b(c1.w);
        const u16* base = smem + cur * 6912;
#pragma unroll
        for (int t = 0; t < 12; ++t) {
            short8 b = *(const short8*)(base + (t * 16 + l16) * 36 + koff);
            acc[t] = MFMA16(a, b, acc[t]);
        }
        if (kc < 7) {
            u16* nb = smem + nxt * 6912;
            *(short8*)(nb + (u0 >> 2) * 36 + (u0 & 3) * 8) = p0;
            *(short8*)(nb + (u1 >> 2) * 36 + (u1 & 3) * 8) = p1;
            *(short8*)(nb + (u2 >> 2) * 36 + (u2 & 3) * 8) = p2;
            __syncthreads();
            c0 = n0; c1 = n1;
        }
    }

    // bf16 partials: Pp[kchunk][row][col]
    const int row = mgroup * 64 + w * 16 + quad * 4;
    u16* dst = Pp + ((size_t)kchunk * 16384 + row) * 192 + l16;
#pragma unroll
    for (int t = 0; t < 12; ++t)
#pragma unroll
        for (int reg = 0; reg < 4; ++reg)
            dst[(size_t)reg * 192 + t * 16] = f2b(acc[t][reg]);
}

// ---------- kernel 3: proj combine — sum 4 bf16 partials, write Kb/Qb/Vt
__global__ __launch_bounds__(256) void projc_kernel(const u16* __restrict__ Pp,
                                                    u16* __restrict__ Kb,
                                                    u16* __restrict__ Qb,
                                                    u16* __restrict__ Vt) {
    __shared__ u16 vtile[64][72];                    // [h][t_local]
    const int tid = threadIdx.x;
    const int r0 = blockIdx.x * 64;

    for (int third = 0; third < 3; ++third) {        // 0:K 1:Q 2:V
#pragma unroll
        for (int i = 0; i < 2; ++i) {
            int lin = i * 256 + tid, row = lin >> 3, cu = lin & 7;  // col = cu*8
            const u16* src = Pp + ((size_t)(r0 + row)) * 192 + third * 64 + cu * 8;
            float s[8];
#pragma unroll
            for (int j = 0; j < 8; ++j) s[j] = 0.0f;
#pragma unroll
            for (int ch = 0; ch < 4; ++ch) {
                short8 v = *(const short8*)(src + (size_t)ch * 16384 * 192);
#pragma unroll
                for (int j = 0; j < 8; ++j) s[j] += b2f((u16)v[j]);
            }
            if (third < 2) {
                u16* dst = (third == 0) ? Kb : Qb;
                short8 o;
#pragma unroll
                for (int j = 0; j < 8; ++j) o[j] = f2b(s[j]);
                *(short8*)(dst + (size_t)(r0 + row) * 64 + cu * 8) = o;
            } else {
#pragma unroll
                for (int j = 0; j < 8; ++j)
                    vtile[cu * 8 + j][row] = f2b(s[j]);   // transpose at write
            }
        }
    }
    __syncthreads();
    const int b = r0 >> 12, t0b = r0 & 4095;
#pragma unroll
    for (int i = 0; i < 2; ++i) {
        int lin = i * 256 + tid, h = lin >> 3, c8 = (lin & 7) << 3;
        *(short8*)(Vt + ((size_t)(b * 64 + h) << 12) + t0b + c8) = *(short8*)&vtile[h][c8];
    }
}

// ---------- kernel 4: split-S flash attention, LDS staged + register prefetch.
// grid (tile=64, chunk=8, batch=4); chunk covers s-tiles [8c, 8c+7] clipped causal.
__global__ __launch_bounds__(256) void attn_kernel(const u16* __restrict__ Kb,
                                                   const u16* __restrict__ Qb,
                                                   const u16* __restrict__ Vt,
                                                   u16* __restrict__ Op,
                                                   float* __restrict__ Ml) {
    const int tile = blockIdx.x, chunk = blockIdx.y, b = blockIdx.z;
    if (chunk * 8 > tile) return;
    __shared__ u16 Qs[64][72];
    __shared__ u16 Vs[64][72];
    __shared__ u16 Ps[4][16][72];
    const int tid = threadIdx.x;
    const int w = tid >> 6, lane = tid & 63, quad = lane >> 4, l16 = lane & 15;
    const int t0 = tile * 64;
    const int stBeg = chunk * 8;
    const int stEnd = min(chunk * 8 + 7, tile);

    // staging indices (each thread moves 2x16B per tile)
    const int lin0 = tid, lin1 = tid + 256;
    const int sr0 = lin0 >> 3, sc0 = (lin0 & 7) << 3;
    const int sr1 = lin1 >> 3, sc1 = (lin1 & 7) << 3;

    short8 aK[2];
#pragma unroll
    for (int kk = 0; kk < 2; ++kk)
        aK[kk] = *(const short8*)(Kb + (size_t)((b << 12) + t0 + w * 16 + l16) * 64 + kk * 32 + quad * 8);

    // prefetch first tile into registers
    short8 qr0 = *(const short8*)(Qb + (size_t)((b << 12) + stBeg * 64 + sr0) * 64 + sc0);
    short8 qr1 = *(const short8*)(Qb + (size_t)((b << 12) + stBeg * 64 + sr1) * 64 + sc1);
    short8 vr0 = *(const short8*)(Vt + (((size_t)(b * 64 + sr0)) << 12) + stBeg * 64 + sc0);
    short8 vr1 = *(const short8*)(Vt + (((size_t)(b * 64 + sr1)) << 12) + stBeg * 64 + sc1);

    float m_s[4], l_s[4];
    f32x4 O[4];
#pragma unroll
    for (int r = 0; r < 4; ++r) { m_s[r] = -1e30f; l_s[r] = 0.0f; }
#pragma unroll
    for (int nt = 0; nt < 4; ++nt) O[nt] = (f32x4)(0.0f);

    const int trow = w * 16 + quad * 4;
    const int tglob = t0 + trow;

    for (int st = stBeg; st <= stEnd; ++st) {
        const int s0 = st * 64;
        __syncthreads();                              // LDS free (prev tile's compute done)
        *(short8*)&Qs[sr0][sc0] = qr0;
        *(short8*)&Qs[sr1][sc1] = qr1;
        *(short8*)&Vs[sr0][sc0] = vr0;
        *(short8*)&Vs[sr1][sc1] = vr1;
        __syncthreads();
        if (st < stEnd) {                             // issue next-tile loads; land during compute
            qr0 = *(const short8*)(Qb + (size_t)((b << 12) + (st + 1) * 64 + sr0) * 64 + sc0);
            qr1 = *(const short8*)(Qb + (size_t)((b << 12) + (st + 1) * 64 + sr1) * 64 + sc1);
            vr0 = *(const short8*)(Vt + (((size_t)(b * 64 + sr0)) << 12) + (st + 1) * 64 + sc0);
            vr1 = *(const short8*)(Vt + (((size_t)(b * 64 + sr1)) << 12) + (st + 1) * 64 + sc1);
        }

        // S = K @ Q^T
        f32x4 sc[4];
#pragma unroll
        for (int nt = 0; nt < 4; ++nt) sc[nt] = (f32x4)(0.0f);
#pragma unroll
        for (int kk = 0; kk < 2; ++kk)
#pragma unroll
            for (int nt = 0; nt < 4; ++nt) {
                short8 bq = *(const short8*)&Qs[nt * 16 + l16][kk * 32 + quad * 8];
                sc[nt] = MFMA16(aK[kk], bq, sc[nt]);
            }

        // scale + causal mask + row max
        float mx[4] = {-1e30f, -1e30f, -1e30f, -1e30f};
#pragma unroll
        for (int nt = 0; nt < 4; ++nt) {
            int sg = s0 + nt * 16 + l16;
#pragma unroll
            for (int reg = 0; reg < 4; ++reg) {
                float v = sc[nt][reg] * 0.125f;
                if (st == tile && sg > tglob + reg) v = -1e30f;
                sc[nt][reg] = v;
                mx[reg] = fmaxf(mx[reg], v);
            }
        }
#pragma unroll
        for (int reg = 0; reg < 4; ++reg) {
            float v = mx[reg];
            v = fmaxf(v, __shfl_xor(v, 1));
            v = fmaxf(v, __shfl_xor(v, 2));
            v = fmaxf(v, __shfl_xor(v, 4));
            v = fmaxf(v, __shfl_xor(v, 8));
            mx[reg] = v;
        }
        float alpha[4], rs[4];
#pragma unroll
        for (int reg = 0; reg < 4; ++reg) {
            float mn = fmaxf(m_s[reg], mx[reg]);
            alpha[reg] = __expf(m_s[reg] - mn);
            m_s[reg] = mn;
            l_s[reg] *= alpha[reg];
            rs[reg] = 0.0f;
        }
#pragma unroll
        for (int nt = 0; nt < 4; ++nt)
#pragma unroll
            for (int reg = 0; reg < 4; ++reg) {
                float p = __expf(sc[nt][reg] - m_s[reg]);
                rs[reg] += p;
                Ps[w][quad * 4 + reg][nt * 16 + l16] = f2b(p);   // wave-private slab
            }
#pragma unroll
        for (int reg = 0; reg < 4; ++reg) {
            float v = rs[reg];
            v += __shfl_xor(v, 1);
            v += __shfl_xor(v, 2);
            v += __shfl_xor(v, 4);
            v += __shfl_xor(v, 8);
            l_s[reg] += v;
        }
#pragma unroll
        for (int nt = 0; nt < 4; ++nt)
#pragma unroll
            for (int reg = 0; reg < 4; ++reg)
                O[nt][reg] *= alpha[reg];

        // PV: A = P from wave-private LDS (same-wave DS ordering, no barrier)
#pragma unroll
        for (int kk = 0; kk < 2; ++kk) {
            short8 ap = *(const short8*)&Ps[w][l16][kk * 32 + quad * 8];
#pragma unroll
            for (int nt = 0; nt < 4; ++nt) {
                short8 bv = *(const short8*)&Vs[nt * 16 + l16][kk * 32 + quad * 8];
                O[nt] = MFMA16(ap, bv, O[nt]);
            }
        }
    }

    const int slot = ((b * 64 + tile) * 8 + chunk);
    if (l16 == 0) {
#pragma unroll
        for (int reg = 0; reg < 4; ++reg) {
            Ml[(size_t)slot * 128 + trow + reg]      = m_s[reg];
            Ml[(size_t)slot * 128 + 64 + trow + reg] = l_s[reg];
        }
    }
#pragma unroll
    for (int nt = 0; nt < 4; ++nt)
#pragma unroll
        for (int reg = 0; reg < 4; ++reg)
            Op[(size_t)slot * 4096 + (size_t)(trow + reg) * 64 + nt * 16 + l16] = f2b(O[nt][reg]);
}

// ---------- kernel 5: combine partials -> out f32 (fully unrolled, NaN-safe predication)
__global__ __launch_bounds__(256) void combine_kernel(const u16* __restrict__ Op,
                                                      const float* __restrict__ Ml,
                                                      float* __restrict__ out) {
    const int tid = threadIdx.x, col = tid & 63, r0 = tid >> 6;
    const int tile = blockIdx.x >> 2, rg = blockIdx.x & 3, b = blockIdx.y;
    const int nch = tile / 8 + 1;
    const int slotBase = (b * 64 + tile) * 8;
#pragma unroll
    for (int i = 0; i < 4; ++i) {
        const int row = rg * 16 + r0 + 4 * i;
        float m[8], l[8], ov[8];
#pragma unroll
        for (int c = 0; c < 8; ++c) {                // all loads issued independently
            const bool act = c < nch;
            float mraw = Ml[(size_t)(slotBase + c) * 128 + row];
            float lraw = Ml[(size_t)(slotBase + c) * 128 + 64 + row];
            u16  oraw = Op[(size_t)(slotBase + c) * 4096 + (size_t)row * 64 + col];
            m[c]  = act ? mraw : -1e30f;             // select BEFORE use (poison may be NaN)
            l[c]  = act ? lraw : 0.0f;
            ov[c] = act ? b2f(oraw) : 0.0f;
        }
        float M = -1e30f;
#pragma unroll
        for (int c = 0; c < 8; ++c) M = fmaxf(M, m[c]);
        float L = 0.0f, acc = 0.0f;
#pragma unroll
        for (int c = 0; c < 8; ++c) {
            float wgt = __expf(m[c] - M);
            L += wgt * l[c];
            acc += wgt * ov[c];
        }
        out[((size_t)(b << 12) + tile * 64 + row) * 64 + col] = acc / L;
    }
}

extern "C" void kernel_launch(void* const* d_in, const int* in_sizes, int n_in,
                              void* d_out, int out_size, void* d_ws, size_t ws_size,
                              hipStream_t stream) {
    const float* x  = (const float*)d_in[0];
    const float* Wk = (const float*)d_in[1];
    const float* Wq = (const float*)d_in[2];
    const float* Wv = (const float*)d_in[3];

    u16* ws16 = (u16*)d_ws;
    u16* Wt = ws16;                          // 196608 u16  (0.4 MB)
    u16* Kb = Wt + 196608;                   // 1048576 u16 (2 MB)
    u16* Qb = Kb + 1048576;
    u16* Vt = Qb + 1048576;
    u16* trans = Vt + 1048576;               // transient (25.2 MB):
    u16* Pp = trans;                         //   Pp: 4*16384*192 u16 (proj phase)
    u16* Op = trans;                         //   Op: 8388608 u16 (attn phase, aliases Pp)
    float* Ml = (float*)(Op + 8388608);      //   Ml: 262144 f32 (fits inside Pp region)
    // total ws ~31.9 MB; aliasing safe: projc reads Pp before attn writes Op/Ml.

    wt_kernel<<<48, 256, 0, stream>>>(Wk, Wq, Wv, Wt);
    proj1_kernel<<<1024, 256, 0, stream>>>(x, Wt, Pp);
    projc_kernel<<<256, 256, 0, stream>>>(Pp, Kb, Qb, Vt);
    attn_kernel<<<dim3(64, 8, 4), 256, 0, stream>>>(Kb, Qb, Vt, Op, Ml);
    combine_kernel<<<dim3(256, 4), 256, 0, stream>>>(Op, Ml, (float*)d_out);
}